// Round 5
// baseline (388.937 us; speedup 1.0000x reference)
//
#include <hip/hip_runtime.h>

#define MROWS 16384
#define KD 2048
#define NQ 256
#define NE 64
#define INV_SQRT_DQ 0.0625f
#define NOISE_STD_C 0.1f

typedef _Float16 f16x8 __attribute__((ext_vector_type(8)));
typedef float f32x4 __attribute__((ext_vector_type(4)));

__device__ inline void split8v(f32x4 a, f32x4 b, f16x8* h, f16x8* l) {
    f16x8 hh, ll;
#pragma unroll
    for (int i = 0; i < 4; ++i) {
        _Float16 s = (_Float16)a[i];
        hh[i] = s; ll[i] = (_Float16)(a[i] - (float)s);
    }
#pragma unroll
    for (int i = 0; i < 4; ++i) {
        _Float16 s = (_Float16)b[i];
        hh[4 + i] = s; ll[4 + i] = (_Float16)(b[i] - (float)s);
    }
    *h = hh; *l = ll;
}

// ---------------------------------------------------------------------------
// Kernel 1: W2 = w_q @ keys.T ([2048][64], fp64 accumulate -> f32), emitted
// B-fragment-packed hi/lo f16. 256 blocks, block o owns k-rows o*8..o*8+7;
// threads (qc,e) q-split-4, LDS combine. css[e] = (b_q.keys[e])/16 by block 0.
// frag layout: off(d,e) = ((d>>5)*4 + (e>>4))*512 + (((d>>3)&3)*16 + (e&15))*8 + (d&7)
__global__ __launch_bounds__(256) void prep_w2(
    const float* __restrict__ w, const float* __restrict__ keys,
    const float* __restrict__ bq, _Float16* __restrict__ whp,
    _Float16* __restrict__ wlp, float* __restrict__ css) {
    __shared__ double part[4][64][8];
    const int t = threadIdx.x;
    const int e = t & 63;
    const int qc = t >> 6;                 // 0..3 q-chunk (and wave id)
    const int o = blockIdx.x;              // 0..255 k-octet
    const float* kp = keys + (size_t)e * NQ + qc * 64;
    const float* wp = w + (size_t)o * 8 * NQ + qc * 64;
    double acc[8];
#pragma unroll
    for (int j = 0; j < 8; ++j) acc[j] = 0.0;
    for (int q = 0; q < 64; q += 4) {
        f32x4 kv = *(const f32x4*)(kp + q);
#pragma unroll
        for (int j = 0; j < 8; ++j) {
            f32x4 wv = *(const f32x4*)(wp + (size_t)j * NQ + q);
#pragma unroll
            for (int u = 0; u < 4; ++u)
                acc[j] += (double)wv[u] * (double)kv[u];
        }
    }
#pragma unroll
    for (int j = 0; j < 8; ++j) part[qc][e][j] = acc[j];
    __syncthreads();
    if (t < 64) {
        const size_t base = ((size_t)(o >> 2) * 4 + (e >> 4)) * 512 +
                            (size_t)((o & 3) * 16 + (e & 15)) * 8;
        f16x8 h, l;
#pragma unroll
        for (int j = 0; j < 8; ++j) {
            float v = (float)(part[0][e][j] + part[1][e][j] +
                              part[2][e][j] + part[3][e][j]);
            _Float16 s = (_Float16)v;
            h[j] = s;
            l[j] = (_Float16)(v - (float)s);
        }
        *(f16x8*)(whp + base) = h;
        *(f16x8*)(wlp + base) = l;
    }
    if (blockIdx.x == 0) {
        __syncthreads();  // packing reads of part[] complete
        double p = 0.0;
        const float* bp2 = bq + qc * 64;
        const float* kp2 = keys + (size_t)e * NQ + qc * 64;
        for (int q = 0; q < 64; q += 4) {
            f32x4 bv = *(const f32x4*)(bp2 + q);
            f32x4 kv = *(const f32x4*)(kp2 + q);
#pragma unroll
            for (int u = 0; u < 4; ++u)
                p += (double)bv[u] * (double)kv[u];
        }
        part[qc][e][0] = p;
        __syncthreads();
        if (t < 64)
            css[e] = (float)((part[0][e][0] + part[1][e][0] +
                              part[2][e][0] + part[3][e][0]) * 0.0625);
    }
}

// ---------------------------------------------------------------------------
// Kernel 2 (MEASUREMENT CONFIG): identical math to round-4 gemm4, but grid 64
// with a 4x m-tile loop per block (each block: 256 rows). Purpose: push this
// dispatch above the 78us poison-fills so it appears in the rocprof top-5
// with its own FETCH_SIZE / MfmaUtil / VALUBusy / hbm_gbps. Also cuts B
// re-read traffic 128MB -> 32MB.
__global__ __launch_bounds__(512, 2) void gemm4_fused(
    const float* __restrict__ x, const _Float16* __restrict__ whp,
    const _Float16* __restrict__ wlp, const float* __restrict__ css,
    const float* __restrict__ noise, float* __restrict__ gate,
    float* __restrict__ idxout) {
    // part[w][row][68] f32 = 139,264 B; LG [64][68] aliases base after reduce.
    __shared__ __align__(16) char smem[139264];

    const int t = threadIdx.x;
    const int lane = t & 63;
    const int wv = t >> 6;             // 0..7: k-chunk [wv*256, wv*256+256)
    const int f = lane & 15;           // row-in-tile / expert-in-tile
    const int qq = lane >> 4;          // k-octet within 32-k step

    // B frag (g,nt) at whp + (g*4+nt)*512 + lane*8 ; this wave: g = wv*8 + s
    const _Float16* bph = whp + (size_t)(wv * 8) * 2048 + lane * 8;
    const _Float16* bpl = wlp + (size_t)(wv * 8) * 2048 + lane * 8;

    for (int mtile = 0; mtile < 4; ++mtile) {
        const int m0 = (blockIdx.x * 4 + mtile) * 64;
        const float* xp = x + (size_t)(m0 + f) * KD + wv * 256 + qq * 8;

        f32x4 acc[4][4];
#pragma unroll
        for (int mt = 0; mt < 4; ++mt)
#pragma unroll
            for (int nt = 0; nt < 4; ++nt) acc[mt][nt] = {0.f, 0.f, 0.f, 0.f};

        f32x4 xr[2][4][2];                 // x ring: [slot][mt][pair]
        f16x8 bhS[2][4], blS[2][4];        // B ring: [slot][nt]

        // prologue: groups 0,1
#pragma unroll
        for (int s = 0; s < 2; ++s) {
#pragma unroll
            for (int mt = 0; mt < 4; ++mt) {
                const f32x4* p = (const f32x4*)(xp + (size_t)mt * 16 * KD + s * 32);
                xr[s][mt][0] = p[0];
                xr[s][mt][1] = p[1];
            }
#pragma unroll
            for (int nt = 0; nt < 4; ++nt) {
                bhS[s][nt] = *(const f16x8*)(bph + (size_t)(s * 4 + nt) * 512);
                blS[s][nt] = *(const f16x8*)(bpl + (size_t)(s * 4 + nt) * 512);
            }
        }

        // 8 k-steps of 32, fully unrolled; refill distance 2.
#pragma unroll
        for (int s = 0; s < 8; ++s) {
            const int cs = s & 1;
#pragma unroll
            for (int mt = 0; mt < 4; ++mt) {
                f16x8 ah, al;
                split8v(xr[cs][mt][0], xr[cs][mt][1], &ah, &al);
                if (s < 6) {               // refill this mt's slot with step s+2
                    const f32x4* p = (const f32x4*)(xp + (size_t)mt * 16 * KD + (s + 2) * 32);
                    xr[cs][mt][0] = p[0];
                    xr[cs][mt][1] = p[1];
                }
#pragma unroll
                for (int nt = 0; nt < 4; ++nt) {
                    acc[mt][nt] = __builtin_amdgcn_mfma_f32_16x16x32_f16(ah, bhS[cs][nt], acc[mt][nt], 0, 0, 0);
                    acc[mt][nt] = __builtin_amdgcn_mfma_f32_16x16x32_f16(ah, blS[cs][nt], acc[mt][nt], 0, 0, 0);
                    acc[mt][nt] = __builtin_amdgcn_mfma_f32_16x16x32_f16(al, bhS[cs][nt], acc[mt][nt], 0, 0, 0);
                }
            }
            if (s < 6) {                   // refill B slot with step s+2 (L2/L3)
#pragma unroll
                for (int nt = 0; nt < 4; ++nt) {
                    bhS[cs][nt] = *(const f16x8*)(bph + (size_t)((s + 2) * 4 + nt) * 512);
                    blS[cs][nt] = *(const f16x8*)(bpl + (size_t)((s + 2) * 4 + nt) * 512);
                }
            }
        }

        // ---- park partials: part[wv][row][e], stride 68
        float* part = (float*)smem;
#pragma unroll
        for (int mt = 0; mt < 4; ++mt)
#pragma unroll
            for (int nt = 0; nt < 4; ++nt)
#pragma unroll
                for (int r = 0; r < 4; ++r)
                    part[(size_t)(wv * 64 + mt * 16 + qq * 4 + r) * 68 + nt * 16 + f] =
                        acc[mt][nt][r];
        __syncthreads();

        // ---- reduce 8 k-chunks: thread t -> row t>>3, expert octet (t&7)*8
        const int rrow = t >> 3;
        const int e0 = (t & 7) * 8;
        f32x4 s0 = {0.f, 0.f, 0.f, 0.f}, s1 = {0.f, 0.f, 0.f, 0.f};
#pragma unroll
        for (int w = 0; w < 8; ++w) {
            const float* pp = part + (size_t)(w * 64 + rrow) * 68 + e0;
            f32x4 u = *(const f32x4*)pp;
            f32x4 v = *(const f32x4*)(pp + 4);
#pragma unroll
            for (int j = 0; j < 4; ++j) { s0[j] += u[j]; s1[j] += v[j]; }
        }
        f32x4 c0 = *(const f32x4*)(css + e0);
        f32x4 c1 = *(const f32x4*)(css + e0 + 4);
        const float* np = noise + (size_t)(m0 + rrow) * NE + e0;
        f32x4 n0 = *(const f32x4*)np;
        f32x4 n1 = *(const f32x4*)(np + 4);
#pragma unroll
        for (int j = 0; j < 4; ++j) {
            s0[j] = s0[j] * INV_SQRT_DQ + c0[j] + NOISE_STD_C * n0[j];
            s1[j] = s1[j] * INV_SQRT_DQ + c1[j] + NOISE_STD_C * n1[j];
        }
        __syncthreads();  // all part[] reads done before LG (aliases base) write

        float* LG = (float*)smem;  // [64][68]
        *(f32x4*)(LG + (size_t)rrow * 68 + e0) = s0;
        *(f32x4*)(LG + (size_t)rrow * 68 + e0 + 4) = s1;
        __syncthreads();

        // ---- top-2 + softmax + scatter: 8 waves x 8 rows, lane = expert
        for (int i = 0; i < 8; ++i) {
            const int r = wv * 8 + i;
            float v = LG[(size_t)r * 68 + lane];
            float v1 = v; int i1 = lane;
#pragma unroll
            for (int off = 32; off; off >>= 1) {
                float ov = __shfl_xor(v1, off);
                int oi = __shfl_xor(i1, off);
                if (ov > v1 || (ov == v1 && oi < i1)) { v1 = ov; i1 = oi; }
            }
            float v2 = (lane == i1) ? -1e30f : v;
            int i2 = lane;
#pragma unroll
            for (int off = 32; off; off >>= 1) {
                float ov = __shfl_xor(v2, off);
                int oi = __shfl_xor(i2, off);
                if (ov > v2 || (ov == v2 && oi < i2)) { v2 = ov; i2 = oi; }
            }
            float ex = expf(v2 - v1);           // v2 <= v1, stable
            float p1 = 1.0f / (1.0f + ex);
            float p2 = ex * p1;
            float g = (lane == i1) ? p1 : ((lane == i2) ? p2 : 0.0f);
            gate[(size_t)(m0 + r) * NE + lane] = g;
            if (lane == 0) {
                float2 ii = make_float2((float)i1, (float)i2);
                *(float2*)(idxout + (size_t)(m0 + r) * 2) = ii;
            }
        }
        __syncthreads();  // LG reads done before next mtile's park overwrites
    }
}

// ---------------------------------------------------------------------------
extern "C" void kernel_launch(void* const* d_in, const int* in_sizes, int n_in,
                              void* d_out, int out_size, void* d_ws, size_t ws_size,
                              hipStream_t stream) {
    const float* x     = (const float*)d_in[0];
    const float* noise = (const float*)d_in[1];
    const float* w_q   = (const float*)d_in[2];
    const float* b_q   = (const float*)d_in[3];
    const float* keys  = (const float*)d_in[4];
    float* out = (float*)d_out;

    char* ws = (char*)d_ws;
    _Float16* whp = (_Float16*)ws;                  // 256 KB, frag-packed hi
    _Float16* wlp = (_Float16*)(ws + (256u << 10)); // 256 KB, frag-packed lo
    float* css    = (float*)(ws + (512u << 10));    // 256 B

    prep_w2<<<256, 256, 0, stream>>>(w_q, keys, b_q, whp, wlp, css);
    gemm4_fused<<<64, 512, 0, stream>>>(x, whp, wlp, css, noise,
                                        out, out + (size_t)MROWS * NE);
}

// Round 6
// 227.368 us; speedup vs baseline: 1.7106x; 1.7106x over previous
//
#include <hip/hip_runtime.h>

#define MROWS 16384
#define KD 2048
#define NQ 256
#define NE 64
#define INV_SQRT_DQ 0.0625f
#define NOISE_STD_C 0.1f

typedef _Float16 f16x8 __attribute__((ext_vector_type(8)));
typedef _Float16 f16x4 __attribute__((ext_vector_type(4)));
typedef float f32x4 __attribute__((ext_vector_type(4)));

__device__ inline void split4v(f32x4 a, f16x4* h, f16x4* l) {
    f16x4 hh, ll;
#pragma unroll
    for (int i = 0; i < 4; ++i) {
        _Float16 s = (_Float16)a[i];
        hh[i] = s; ll[i] = (_Float16)(a[i] - (float)s);
    }
    *h = hh; *l = ll;
}

// ---------------------------------------------------------------------------
// Kernel 1: W2 = w_q @ keys.T ([2048][64], fp64 accumulate -> f32), emitted
// B-fragment-packed hi/lo f16. 256 blocks, block o owns k-rows o*8..o*8+7;
// threads (qc,e) q-split-4, LDS combine. css[e] = (b_q.keys[e])/16 by block 0.
// frag layout: off(d,e) = ((d>>5)*4 + (e>>4))*512 + (((d>>3)&3)*16 + (e&15))*8 + (d&7)
__global__ __launch_bounds__(256) void prep_w2(
    const float* __restrict__ w, const float* __restrict__ keys,
    const float* __restrict__ bq, _Float16* __restrict__ whp,
    _Float16* __restrict__ wlp, float* __restrict__ css) {
    __shared__ double part[4][64][8];
    const int t = threadIdx.x;
    const int e = t & 63;
    const int qc = t >> 6;                 // 0..3 q-chunk (and wave id)
    const int o = blockIdx.x;              // 0..255 k-octet
    const float* kp = keys + (size_t)e * NQ + qc * 64;
    const float* wp = w + (size_t)o * 8 * NQ + qc * 64;
    double acc[8];
#pragma unroll
    for (int j = 0; j < 8; ++j) acc[j] = 0.0;
    for (int q = 0; q < 64; q += 4) {
        f32x4 kv = *(const f32x4*)(kp + q);
#pragma unroll
        for (int j = 0; j < 8; ++j) {
            f32x4 wv = *(const f32x4*)(wp + (size_t)j * NQ + q);
#pragma unroll
            for (int u = 0; u < 4; ++u)
                acc[j] += (double)wv[u] * (double)kv[u];
        }
    }
#pragma unroll
    for (int j = 0; j < 8; ++j) part[qc][e][j] = acc[j];
    __syncthreads();
    if (t < 64) {
        const size_t base = ((size_t)(o >> 2) * 4 + (e >> 4)) * 512 +
                            (size_t)((o & 3) * 16 + (e & 15)) * 8;
        f16x8 h, l;
#pragma unroll
        for (int j = 0; j < 8; ++j) {
            float v = (float)(part[0][e][j] + part[1][e][j] +
                              part[2][e][j] + part[3][e][j]);
            _Float16 s = (_Float16)v;
            h[j] = s;
            l[j] = (_Float16)(v - (float)s);
        }
        *(f16x8*)(whp + base) = h;
        *(f16x8*)(wlp + base) = l;
    }
    if (blockIdx.x == 0) {
        __syncthreads();  // packing reads of part[] complete
        double p = 0.0;
        const float* bp2 = bq + qc * 64;
        const float* kp2 = keys + (size_t)e * NQ + qc * 64;
        for (int q = 0; q < 64; q += 4) {
            f32x4 bv = *(const f32x4*)(bp2 + q);
            f32x4 kv = *(const f32x4*)(kp2 + q);
#pragma unroll
            for (int u = 0; u < 4; ++u)
                p += (double)bv[u] * (double)kv[u];
        }
        part[qc][e][0] = p;
        __syncthreads();
        if (t < 64)
            css[e] = (float)((part[0][e][0] + part[1][e][0] +
                              part[2][e][0] + part[3][e][0]) * 0.0625);
    }
}

// ---------------------------------------------------------------------------
// Kernel 2: logits = x @ W2 (3-pass f16-split MFMA) + css + noise, top-2 +
// softmax + scatter. KEY FIX vs r0-r5: x staging loads are fully coalesced
// (per wave-instruction: 4 rows x 256B dense; previously 16B-at-32B-stride
// across 8-16 rows => ~32 partial segments/instr => transaction-rate wall,
// all pipes <6% busy). LDS skeleton = r0's zero-conflict geometry: BK=64,
// [64][64] f16 hi+lo, XOR octet swizzle, ping-pong, lgkm-only barrier.
// Waves 2m x 4n (wave = 32 rows x 16 experts); rolling depth-4 B-frag regs.
// grid 256, 512 threads.
__global__ __launch_bounds__(512) void gemm5_fused(
    const float* __restrict__ x, const _Float16* __restrict__ whp,
    const _Float16* __restrict__ wlp, const float* __restrict__ css,
    const float* __restrict__ noise, float* __restrict__ gate,
    float* __restrict__ idxout) {
    // buf b at b*16384 B: {Ah 8KB [64][64]f16, Al 8KB}. Epilogue LG[64][68]
    // f32 (17.4KB) aliases base after final barrier.
    __shared__ __align__(16) char smem[32768];

    const int t = threadIdx.x;
    const int lane = t & 63;
    const int wv = t >> 6;              // 0..7
    const int wn = wv & 3;              // expert tile: [wn*16, wn*16+16)
    const int wm = wv >> 2;             // row half: [wm*32, wm*32+32)
    const int m0 = blockIdx.x * 64;
    const int f = lane & 15;
    const int qq = lane >> 4;           // 0..3

    // staging: thread t -> row sr & sr+32, 16B col sc. Dense per instruction.
    const int sr = t >> 4;              // 0..31
    const int sc = t & 15;              // 16B column within 256B row-chunk
    const int soct = sc >> 1;           // octet 0..7
    const int shalf = sc & 1;
    const float* xp0 = x + (size_t)(m0 + sr) * KD + sc * 4;
    const float* xp1 = x + (size_t)(m0 + sr + 32) * KD + sc * 4;
    // LDS write offsets (f16 units); (sr+32)&7 == sr&7 so same swizzle
    const int wde0 = sr * 64 + ((soct ^ (sr & 7)) * 8) + shalf * 4;
    const int wde1 = wde0 + 32 * 64;

    // B pointers (frag-packed): frag (g, wn) at whp + (g*4+wn)*512 + lane*8
    const _Float16* bph = whp + (size_t)wn * 512 + lane * 8;
    const _Float16* bpl = wlp + (size_t)wn * 512 + lane * 8;

    f32x4 acc[2];
    acc[0] = {0.f, 0.f, 0.f, 0.f};
    acc[1] = {0.f, 0.f, 0.f, 0.f};

    // rolling B slots (depth 4 g-steps = 2 iterations of slack)
    f16x8 bhS[4], blS[4];
#pragma unroll
    for (int s = 0; s < 4; ++s) {
        bhS[s] = *(const f16x8*)(bph + (size_t)s * 2048);
        blS[s] = *(const f16x8*)(bpl + (size_t)s * 2048);
    }

    // x prefetch pairs by tile parity: pair[p] holds tile with tile&1==p.
    f32x4 e0, e1, o0, o1;
    // prologue: tile0 -> stage buf0; load tile1 (odd pair), tile2 (even pair)
    e0 = *(const f32x4*)xp0;
    e1 = *(const f32x4*)xp1;
    {
        _Float16* Ah = (_Float16*)smem;
        _Float16* Al = Ah + 4096;
        f16x4 h, l;
        split4v(e0, &h, &l);
        *(f16x4*)(Ah + wde0) = h; *(f16x4*)(Al + wde0) = l;
        split4v(e1, &h, &l);
        *(f16x4*)(Ah + wde1) = h; *(f16x4*)(Al + wde1) = l;
    }
    o0 = *(const f32x4*)(xp0 + 64);
    o1 = *(const f32x4*)(xp1 + 64);
    e0 = *(const f32x4*)(xp0 + 128);
    e1 = *(const f32x4*)(xp1 + 128);
    __syncthreads();  // one-time full drain

    // ---- K loop: 32 tiles of BK=64, unrolled x2 so all reg indices static.
    for (int ii = 0; ii < 16; ++ii) {
#pragma unroll
        for (int j = 0; j < 2; ++j) {
            const int i = ii * 2 + j;                       // tile index
            _Float16* AhC = (_Float16*)smem + j * 8192;     // tile i in buf j
            _Float16* AlC = AhC + 4096;
            _Float16* AhN = (_Float16*)smem + (j ^ 1) * 8192;
            _Float16* AlN = AhN + 4096;

            // stage tile i+1 (parity j^1 pair) into other buffer
            if (i < 31) {
                f16x4 h, l;
                if (j == 0) {
                    split4v(o0, &h, &l);
                    *(f16x4*)(AhN + wde0) = h; *(f16x4*)(AlN + wde0) = l;
                    split4v(o1, &h, &l);
                    *(f16x4*)(AhN + wde1) = h; *(f16x4*)(AlN + wde1) = l;
                } else {
                    split4v(e0, &h, &l);
                    *(f16x4*)(AhN + wde0) = h; *(f16x4*)(AlN + wde0) = l;
                    split4v(e1, &h, &l);
                    *(f16x4*)(AhN + wde1) = h; *(f16x4*)(AlN + wde1) = l;
                }
            }
            // refill the pair just consumed with tile i+3 (2 iters of slack)
            if (i < 29) {
                if (j == 0) {
                    o0 = *(const f32x4*)(xp0 + (i + 3) * 64);
                    o1 = *(const f32x4*)(xp1 + (i + 3) * 64);
                } else {
                    e0 = *(const f32x4*)(xp0 + (i + 3) * 64);
                    e1 = *(const f32x4*)(xp1 + (i + 3) * 64);
                }
            }
            // compute tile i: 2 k-steps of 32
#pragma unroll
            for (int ks = 0; ks < 2; ++ks) {
                const int slot = (2 * j + ks) & 3;          // static
                f16x8 ah[2], al[2];
#pragma unroll
                for (int mt = 0; mt < 2; ++mt) {
                    const int row = wm * 32 + mt * 16 + f;
                    const int off = row * 64 + (((ks * 4 + qq) ^ (f & 7)) * 8);
                    ah[mt] = *(const f16x8*)(AhC + off);
                    al[mt] = *(const f16x8*)(AlC + off);
                }
#pragma unroll
                for (int mt = 0; mt < 2; ++mt) {
                    acc[mt] = __builtin_amdgcn_mfma_f32_16x16x32_f16(ah[mt], bhS[slot], acc[mt], 0, 0, 0);
                    acc[mt] = __builtin_amdgcn_mfma_f32_16x16x32_f16(ah[mt], blS[slot], acc[mt], 0, 0, 0);
                    acc[mt] = __builtin_amdgcn_mfma_f32_16x16x32_f16(al[mt], bhS[slot], acc[mt], 0, 0, 0);
                }
                int gn = 2 * i + ks + 4;
                if (gn > 63) gn = 63;   // clamped redundant tail loads
                bhS[slot] = *(const f16x8*)(bph + (size_t)gn * 2048);
                blS[slot] = *(const f16x8*)(bpl + (size_t)gn * 2048);
            }
            // publish LDS writes without draining vmcnt (prefetches stay live)
            asm volatile("" ::: "memory");
            __builtin_amdgcn_s_waitcnt(0xC07F);  // lgkmcnt(0) only
            __builtin_amdgcn_s_barrier();
            asm volatile("" ::: "memory");
        }
    }

    __syncthreads();  // drain; LDS reused as LG

    // ---- epilogue: logits = acc*1/16 + css[e] + 0.1*noise -> LG [64][68]
    float* LG = (float*)smem;
    const int e = wn * 16 + f;
    const float cse = css[e];
#pragma unroll
    for (int mt = 0; mt < 2; ++mt)
#pragma unroll
        for (int r = 0; r < 4; ++r) {
            const int row = wm * 32 + mt * 16 + qq * 4 + r;
            LG[row * 68 + e] = acc[mt][r] * INV_SQRT_DQ + cse +
                               NOISE_STD_C * noise[(size_t)(m0 + row) * NE + e];
        }
    __syncthreads();

    // ---- top-2 + softmax + scatter: 8 waves x 8 rows, lane = expert
    for (int i = 0; i < 8; ++i) {
        const int r = wv * 8 + i;
        float v = LG[r * 68 + lane];
        float v1 = v; int i1 = lane;
#pragma unroll
        for (int off = 32; off; off >>= 1) {
            float ov = __shfl_xor(v1, off);
            int oi = __shfl_xor(i1, off);
            if (ov > v1 || (ov == v1 && oi < i1)) { v1 = ov; i1 = oi; }
        }
        float v2 = (lane == i1) ? -1e30f : v;
        int i2 = lane;
#pragma unroll
        for (int off = 32; off; off >>= 1) {
            float ov = __shfl_xor(v2, off);
            int oi = __shfl_xor(i2, off);
            if (ov > v2 || (ov == v2 && oi < i2)) { v2 = ov; i2 = oi; }
        }
        float ex = expf(v2 - v1);           // v2 <= v1, stable
        float p1 = 1.0f / (1.0f + ex);
        float p2 = ex * p1;
        float g = (lane == i1) ? p1 : ((lane == i2) ? p2 : 0.0f);
        gate[(size_t)(m0 + r) * NE + lane] = g;
        if (lane == 0) {
            float2 ii = make_float2((float)i1, (float)i2);
            *(float2*)(idxout + (size_t)(m0 + r) * 2) = ii;
        }
    }
}

// ---------------------------------------------------------------------------
extern "C" void kernel_launch(void* const* d_in, const int* in_sizes, int n_in,
                              void* d_out, int out_size, void* d_ws, size_t ws_size,
                              hipStream_t stream) {
    const float* x     = (const float*)d_in[0];
    const float* noise = (const float*)d_in[1];
    const float* w_q   = (const float*)d_in[2];
    const float* b_q   = (const float*)d_in[3];
    const float* keys  = (const float*)d_in[4];
    float* out = (float*)d_out;

    char* ws = (char*)d_ws;
    _Float16* whp = (_Float16*)ws;                  // 256 KB, frag-packed hi
    _Float16* wlp = (_Float16*)(ws + (256u << 10)); // 256 KB, frag-packed lo
    float* css    = (float*)(ws + (512u << 10));    // 256 B

    prep_w2<<<256, 256, 0, stream>>>(w_q, keys, b_q, whp, wlp, css);
    gemm5_fused<<<256, 512, 0, stream>>>(x, whp, wlp, css, noise,
                                         out, out + (size_t)MROWS * NE);
}

// Round 7
// 225.273 us; speedup vs baseline: 1.7265x; 1.0093x over previous
//
#include <hip/hip_runtime.h>

#define MROWS 16384
#define KD 2048
#define NQ 256
#define NE 64
#define INV_SQRT_DQ 0.0625f
#define NOISE_STD_C 0.1f

typedef _Float16 f16x8 __attribute__((ext_vector_type(8)));
typedef float f32x4 __attribute__((ext_vector_type(4)));

__device__ __forceinline__ void split8v(f32x4 a, f32x4 b, f16x8* h, f16x8* l) {
    f16x8 hh, ll;
#pragma unroll
    for (int i = 0; i < 4; ++i) {
        _Float16 s = (_Float16)a[i];
        hh[i] = s; ll[i] = (_Float16)(a[i] - (float)s);
    }
#pragma unroll
    for (int i = 0; i < 4; ++i) {
        _Float16 s = (_Float16)b[i];
        hh[4 + i] = s; ll[4 + i] = (_Float16)(b[i] - (float)s);
    }
    *h = hh; *l = ll;
}

// 16B-per-lane async DMA global->LDS. lds dest must be wave-uniform; HW adds
// lane*16. Source is per-lane.
__device__ __forceinline__ void dma16(const void* g, void* l) {
    __builtin_amdgcn_global_load_lds(
        (const __attribute__((address_space(1))) void*)g,
        (__attribute__((address_space(3))) void*)l, 16, 0, 0);
}

// ---------------------------------------------------------------------------
// Kernel 1: W2 = w_q @ keys.T ([2048][64], fp64 accumulate -> f32), emitted
// B-fragment-packed hi/lo f16. 256 blocks, block o owns k-rows o*8..o*8+7;
// threads (qc,e) q-split-4, LDS combine. css[e] = (b_q.keys[e])/16 by block 0.
// frag layout: off(d,e) = ((d>>5)*4 + (e>>4))*512 + (((d>>3)&3)*16 + (e&15))*8 + (d&7)
__global__ __launch_bounds__(256) void prep_w2(
    const float* __restrict__ w, const float* __restrict__ keys,
    const float* __restrict__ bq, _Float16* __restrict__ whp,
    _Float16* __restrict__ wlp, float* __restrict__ css) {
    __shared__ double part[4][64][8];
    const int t = threadIdx.x;
    const int e = t & 63;
    const int qc = t >> 6;                 // 0..3 q-chunk (and wave id)
    const int o = blockIdx.x;              // 0..255 k-octet
    const float* kp = keys + (size_t)e * NQ + qc * 64;
    const float* wp = w + (size_t)o * 8 * NQ + qc * 64;
    double acc[8];
#pragma unroll
    for (int j = 0; j < 8; ++j) acc[j] = 0.0;
    for (int q = 0; q < 64; q += 4) {
        f32x4 kv = *(const f32x4*)(kp + q);
#pragma unroll
        for (int j = 0; j < 8; ++j) {
            f32x4 wv = *(const f32x4*)(wp + (size_t)j * NQ + q);
#pragma unroll
            for (int u = 0; u < 4; ++u)
                acc[j] += (double)wv[u] * (double)kv[u];
        }
    }
#pragma unroll
    for (int j = 0; j < 8; ++j) part[qc][e][j] = acc[j];
    __syncthreads();
    if (t < 64) {
        const size_t base = ((size_t)(o >> 2) * 4 + (e >> 4)) * 512 +
                            (size_t)((o & 3) * 16 + (e & 15)) * 8;
        f16x8 h, l;
#pragma unroll
        for (int j = 0; j < 8; ++j) {
            float v = (float)(part[0][e][j] + part[1][e][j] +
                              part[2][e][j] + part[3][e][j]);
            _Float16 s = (_Float16)v;
            h[j] = s;
            l[j] = (_Float16)(v - (float)s);
        }
        *(f16x8*)(whp + base) = h;
        *(f16x8*)(wlp + base) = l;
    }
    if (blockIdx.x == 0) {
        __syncthreads();  // packing reads of part[] complete
        double p = 0.0;
        const float* bp2 = bq + qc * 64;
        const float* kp2 = keys + (size_t)e * NQ + qc * 64;
        for (int q = 0; q < 64; q += 4) {
            f32x4 bv = *(const f32x4*)(bp2 + q);
            f32x4 kv = *(const f32x4*)(kp2 + q);
#pragma unroll
            for (int u = 0; u < 4; ++u)
                p += (double)bv[u] * (double)kv[u];
        }
        part[qc][e][0] = p;
        __syncthreads();
        if (t < 64)
            css[e] = (float)((part[0][e][0] + part[1][e][0] +
                              part[2][e][0] + part[3][e][0]) * 0.0625);
    }
}

// ---------------------------------------------------------------------------
// Kernel 2: logits = x @ W2 (3-pass f16-split MFMA) + css + noise, top-2 +
// softmax + scatter. ALL K-loop VMEM via global_load_lds DMA (x AND B):
// deterministic FIFO, hand-counted vmcnt(8) keeps 2-3 tile batches in flight
// (~96KB/CU), distance-3 prefetch into a 4-deep LDS ring. No ds_writes, no
// register load rings. x source pre-swizzled per 16B cell (cell ^ (row&15))
// so the linear DMA dest yields ~2-way-conflict fragment reads.
// grid 256, 512 threads (8 waves: wn=wv&3 expert tile, wm=wv>>2 row half).
__global__ __launch_bounds__(512) void gemm6_fused(
    const float* __restrict__ x, const _Float16* __restrict__ whp,
    const _Float16* __restrict__ wlp, const float* __restrict__ css,
    const float* __restrict__ noise, float* __restrict__ gate,
    float* __restrict__ idxout) {
    // [0,64K): x ring, 4 slots x 16KB ([64 rows][16 cells of 16B], swizzled)
    // [64K,128K): B ring, 4 slots x 16KB (hi 8KB: [gs][wn][1KB frag]; lo +8KB)
    // Epilogue LG[64][68] f32 (17.4KB) aliases base after final __syncthreads.
    __shared__ __align__(16) char smem[131072];

    const int t = threadIdx.x;
    const int lane = t & 63;
    const int wv = t >> 6;              // 0..7
    const int wn = wv & 3;              // expert tile [wn*16, wn*16+16)
    const int wm = wv >> 2;             // row half [wm*32, wm*32+32)
    const int m0 = blockIdx.x * 64;
    const int f = lane & 15;
    const int qq = lane >> 4;           // 0..3

    // ---- DMA source/dest setup
    // x: thread t -> (sr = t>>4, sc = t&15); stages global cell sc^(sr&15) of
    // rows sr and sr+32 into LDS cell sc (involution; (sr+32)&15 == sr&15).
    const int sr = t >> 4;
    const int sc = t & 15;
    const float* xs0 = x + (size_t)(m0 + sr) * KD + (sc ^ (sr & 15)) * 4;
    const float* xs1 = xs0 + (size_t)32 * KD;
    const int xdst = wv * 1024;                         // wave-uniform
    // B: wave stages frag (g = 2t+gs, wn), gs = wv>>2, hi from whp, lo wlp.
    const int bdst = (wv >> 2) * 4096 + wn * 1024;      // wave-uniform
    const char* bsh = (const char*)whp + (size_t)((wv >> 2) * 4 + wn) * 1024 + lane * 16;
    const char* bsl = (const char*)wlp + (size_t)((wv >> 2) * 4 + wn) * 1024 + lane * 16;

    // ---- fragment-read offsets (bytes within an x slot)
    const int rb0 = (wm * 32 + f) * 256;                // mt=0 row base
    const int rb1 = rb0 + 4096;                         // mt=1 (+16 rows)
    const int ck0 = ((qq * 2) ^ f) * 16;                // ks=0 cell (swizzled)
    const int ck1 = ((8 + qq * 2) ^ f) * 16;            // ks=1 cell

    f32x4 acc[2];
    acc[0] = {0.f, 0.f, 0.f, 0.f};
    acc[1] = {0.f, 0.f, 0.f, 0.f};

#define ISSUE(t_, s_)                                                          \
    do {                                                                       \
        dma16(xs0 + (t_) * 64, smem + (s_) * 16384 + xdst);                    \
        dma16(xs1 + (t_) * 64, smem + (s_) * 16384 + xdst + 8192);             \
        dma16(bsh + (size_t)(t_) * 8192, smem + 65536 + (s_) * 16384 + bdst);  \
        dma16(bsl + (size_t)(t_) * 8192,                                       \
              smem + 65536 + (s_) * 16384 + bdst + 8192);                      \
    } while (0)

#define COMPUTE(s_)                                                            \
    do {                                                                       \
        const char* xb = smem + (s_) * 16384;                                  \
        const char* bb = smem + 65536 + (s_) * 16384 + wn * 1024 + lane * 16;  \
        f16x8 bh0 = *(const f16x8*)(bb);                                       \
        f16x8 bl0 = *(const f16x8*)(bb + 8192);                                \
        f16x8 bh1 = *(const f16x8*)(bb + 4096);                                \
        f16x8 bl1 = *(const f16x8*)(bb + 4096 + 8192);                         \
        f16x8 ah0, al0, ah1, al1;                                              \
        {                                                                      \
            f32x4 u0 = *(const f32x4*)(xb + rb0 + ck0);                        \
            f32x4 v0 = *(const f32x4*)(xb + rb0 + (ck0 ^ 16));                 \
            f32x4 u1 = *(const f32x4*)(xb + rb1 + ck0);                        \
            f32x4 v1 = *(const f32x4*)(xb + rb1 + (ck0 ^ 16));                 \
            split8v(u0, v0, &ah0, &al0);                                       \
            split8v(u1, v1, &ah1, &al1);                                       \
            acc[0] = __builtin_amdgcn_mfma_f32_16x16x32_f16(ah0, bh0, acc[0], 0, 0, 0); \
            acc[0] = __builtin_amdgcn_mfma_f32_16x16x32_f16(ah0, bl0, acc[0], 0, 0, 0); \
            acc[0] = __builtin_amdgcn_mfma_f32_16x16x32_f16(al0, bh0, acc[0], 0, 0, 0); \
            acc[1] = __builtin_amdgcn_mfma_f32_16x16x32_f16(ah1, bh0, acc[1], 0, 0, 0); \
            acc[1] = __builtin_amdgcn_mfma_f32_16x16x32_f16(ah1, bl0, acc[1], 0, 0, 0); \
            acc[1] = __builtin_amdgcn_mfma_f32_16x16x32_f16(al1, bh0, acc[1], 0, 0, 0); \
        }                                                                      \
        {                                                                      \
            f32x4 u0 = *(const f32x4*)(xb + rb0 + ck1);                        \
            f32x4 v0 = *(const f32x4*)(xb + rb0 + (ck1 ^ 16));                 \
            f32x4 u1 = *(const f32x4*)(xb + rb1 + ck1);                        \
            f32x4 v1 = *(const f32x4*)(xb + rb1 + (ck1 ^ 16));                 \
            split8v(u0, v0, &ah0, &al0);                                       \
            split8v(u1, v1, &ah1, &al1);                                       \
            acc[0] = __builtin_amdgcn_mfma_f32_16x16x32_f16(ah0, bh1, acc[0], 0, 0, 0); \
            acc[0] = __builtin_amdgcn_mfma_f32_16x16x32_f16(ah0, bl1, acc[0], 0, 0, 0); \
            acc[0] = __builtin_amdgcn_mfma_f32_16x16x32_f16(al0, bh1, acc[0], 0, 0, 0); \
            acc[1] = __builtin_amdgcn_mfma_f32_16x16x32_f16(ah1, bh1, acc[1], 0, 0, 0); \
            acc[1] = __builtin_amdgcn_mfma_f32_16x16x32_f16(ah1, bl1, acc[1], 0, 0, 0); \
            acc[1] = __builtin_amdgcn_mfma_f32_16x16x32_f16(al1, bh1, acc[1], 0, 0, 0); \
        }                                                                      \
    } while (0)

#define WAITBAR(vm_)                                                           \
    do {                                                                       \
        asm volatile("s_waitcnt vmcnt(" #vm_ ")" ::: "memory");                \
        __builtin_amdgcn_s_barrier();                                          \
        __builtin_amdgcn_sched_barrier(0);                                     \
    } while (0)

    // prologue: batches for tiles 0..2 (12 DMA ops in flight)
    ISSUE(0, 0);
    ISSUE(1, 1);
    ISSUE(2, 2);

    // main loop: tiles 0..27. Per iter: retire batch i (keep 8 newest = i+1,
    // i+2 prefetches), barrier, issue i+3 (slot (i+3)&3, last read 2 barriers
    // ago -> WAR-safe), compute tile i.
    for (int ii = 0; ii < 7; ++ii) {
#pragma unroll
        for (int u = 0; u < 4; ++u) {
            const int i = ii * 4 + u;
            WAITBAR(8);
            ISSUE(i + 3, (u + 3) & 3);
            COMPUTE(u);
        }
    }
    // tail: tiles 28..31 (peeled; vmcnt tightens as FIFO drains)
    WAITBAR(8); ISSUE(31, 3); COMPUTE(0);   // i=28
    WAITBAR(8); COMPUTE(1);                 // i=29
    WAITBAR(4); COMPUTE(2);                 // i=30
    WAITBAR(0); COMPUTE(3);                 // i=31

#undef ISSUE
#undef COMPUTE
#undef WAITBAR

    __syncthreads();  // full drain; LDS reused as LG

    // ---- epilogue: logits = acc*1/16 + css[e] + 0.1*noise -> LG [64][68]
    float* LG = (float*)smem;
    const int e = wn * 16 + f;
    const float cse = css[e];
#pragma unroll
    for (int mt = 0; mt < 2; ++mt)
#pragma unroll
        for (int r = 0; r < 4; ++r) {
            const int row = wm * 32 + mt * 16 + qq * 4 + r;
            LG[row * 68 + e] = acc[mt][r] * INV_SQRT_DQ + cse +
                               NOISE_STD_C * noise[(size_t)(m0 + row) * NE + e];
        }
    __syncthreads();

    // ---- top-2 + softmax + scatter: 8 waves x 8 rows, lane = expert
    for (int i = 0; i < 8; ++i) {
        const int r = wv * 8 + i;
        float v = LG[r * 68 + lane];
        float v1 = v; int i1 = lane;
#pragma unroll
        for (int off = 32; off; off >>= 1) {
            float ov = __shfl_xor(v1, off);
            int oi = __shfl_xor(i1, off);
            if (ov > v1 || (ov == v1 && oi < i1)) { v1 = ov; i1 = oi; }
        }
        float v2 = (lane == i1) ? -1e30f : v;
        int i2 = lane;
#pragma unroll
        for (int off = 32; off; off >>= 1) {
            float ov = __shfl_xor(v2, off);
            int oi = __shfl_xor(i2, off);
            if (ov > v2 || (ov == v2 && oi < i2)) { v2 = ov; i2 = oi; }
        }
        float ex = expf(v2 - v1);           // v2 <= v1, stable
        float p1 = 1.0f / (1.0f + ex);
        float p2 = ex * p1;
        float g = (lane == i1) ? p1 : ((lane == i2) ? p2 : 0.0f);
        gate[(size_t)(m0 + r) * NE + lane] = g;
        if (lane == 0) {
            float2 ii2 = make_float2((float)i1, (float)i2);
            *(float2*)(idxout + (size_t)(m0 + r) * 2) = ii2;
        }
    }
}

// ---------------------------------------------------------------------------
extern "C" void kernel_launch(void* const* d_in, const int* in_sizes, int n_in,
                              void* d_out, int out_size, void* d_ws, size_t ws_size,
                              hipStream_t stream) {
    const float* x     = (const float*)d_in[0];
    const float* noise = (const float*)d_in[1];
    const float* w_q   = (const float*)d_in[2];
    const float* b_q   = (const float*)d_in[3];
    const float* keys  = (const float*)d_in[4];
    float* out = (float*)d_out;

    char* ws = (char*)d_ws;
    _Float16* whp = (_Float16*)ws;                  // 256 KB, frag-packed hi
    _Float16* wlp = (_Float16*)(ws + (256u << 10)); // 256 KB, frag-packed lo
    float* css    = (float*)(ws + (512u << 10));    // 256 B

    prep_w2<<<256, 256, 0, stream>>>(w_q, keys, b_q, whp, wlp, css);
    gemm6_fused<<<256, 512, 0, stream>>>(x, whp, wlp, css, noise,
                                         out, out + (size_t)MROWS * NE);
}